// Round 7
// baseline (345.882 us; speedup 1.0000x reference)
//
#include <hip/hip_runtime.h>
#include <math.h>

#define BATCH   32768
#define NCLS    1000
#define NC4     250              // 1000/4 float4 chunks per row
#define NBLOCKS 2048
#define NWAVES  (NBLOCKS * 4)    // 8192 waves
#define RPW     (BATCH / NWAVES) // 4 rows per wave

// Proven (R5/R6): 'nt' on streamed loads = -23 us (stops single-touch reads
// from allocating + evicting dirty fill lines; 65 MB/dispatch of writebacks
// gone). sc1 (device scope / L1 bypass) was null on top -> policy axis closed.
// Core structure below is byte-identical to round 6; this round's single
// variable is fusing the reduce kernel away (last-block pattern).
#define GLOAD4(dst, ptr) \
    asm volatile("global_load_dwordx4 %0, %1, off sc1 nt" : "=v"(dst) : "v"(ptr) : "memory")

// Counted wait + sched_barrier(0): rule #18 — without the barrier, hipcc
// hoists register-only consumers above an inline-asm waitcnt.
#define WAITVM(N) do { \
    asm volatile("s_waitcnt vmcnt(" #N ")" ::: "memory"); \
    __builtin_amdgcn_sched_barrier(0); \
} while (0)

// One transcendental per element; w=0 kills the contribution of clamped
// tail lanes exactly (adds 0.0f, bit-exact vs branching them off).
__device__ __forceinline__ void acc4w(float4 xv, int4 tv, float w,
                                      float& sn, float& sp) {
    float e0 = w * __expf(tv.x == 0 ? xv.x : -xv.x);
    float e1 = w * __expf(tv.y == 0 ? xv.y : -xv.y);
    float e2 = w * __expf(tv.z == 0 ? xv.z : -xv.z);
    float e3 = w * __expf(tv.w == 0 ? xv.w : -xv.w);
    sn += (tv.x == 0) ? e0 : 0.0f;  sp += (tv.x == 0) ? 0.0f : e0;
    sn += (tv.y == 0) ? e1 : 0.0f;  sp += (tv.y == 0) ? 0.0f : e1;
    sn += (tv.z == 0) ? e2 : 0.0f;  sp += (tv.z == 0) ? 0.0f : e2;
    sn += (tv.w == 0) ? e3 : 0.0f;  sp += (tv.w == 0) ? 0.0f : e3;
}

// Asm-enforced depth-16 'nt' pipeline (core identical to rounds 4-6) with a
// fused single-kernel finish: each block stores its partial to block_out
// (index-ordered -> bit-stable final sum, same order as the old two-kernel
// version), agent-scope fence, atomic done-counter; the LAST block re-reads
// all 2048 partials (fence invalidates L1/L2 per G16 XCD non-coherence) and
// writes log1p. Removes the ~16 us reduce-kernel launch+exec from the
// critical path; the read core is untouched (it is at the ~3.5 TB/s
// empirical read ceiling: exceeds m13 copy's 3.15 TB/s read side, invariant
// to MLP depth, occupancy, staging mechanism, and data source).
__global__ __launch_bounds__(256, 4) void lsep_row_kernel(
    const float* __restrict__ x,
    const int*   __restrict__ t,
    float* __restrict__ block_out,        // [NBLOCKS] partials (ws)
    unsigned* __restrict__ done_counter,  // zeroed via hipMemsetAsync
    float* __restrict__ out) {

    const int tid   = threadIdx.x;
    const int lane  = tid & 63;
    const int wv    = tid >> 6;
    const int gwave = blockIdx.x * 4 + wv;           // 0..NWAVES-1

    // chunk 3 is partial (250 = 3*64 + 58): lanes 58-63 load chunk 249
    // (in-bounds dummy) and contribute 0 via w3.
    const int   cid3 = (lane < 58) ? (192 + lane) : 249;
    const float w3   = (lane < 58) ? 1.0f : 0.0f;

    const size_t rstep = (size_t)NWAVES * NC4;       // float4 stride per +NWAVES rows
    const float4* xp = (const float4*)x + (size_t)gwave * NC4;
    const int4*   tp = (const int4*)t + (size_t)gwave * NC4;

    float4 xa0, xa1, xa2, xa3, xb0, xb1, xb2, xb3;
    int4   ta0, ta1, ta2, ta3, tb0, tb1, tb2, tb3;

    // Issue one row's 8 loads: x-burst then t-burst (longer per-stream runs).
    #define ISSUE_A(r) do { const float4* xr = xp + (size_t)(r) * rstep; \
                            const int4*   tr = tp + (size_t)(r) * rstep; \
        GLOAD4(xa0, xr + lane); GLOAD4(xa1, xr + 64 + lane); \
        GLOAD4(xa2, xr + 128 + lane); GLOAD4(xa3, xr + cid3); \
        GLOAD4(ta0, tr + lane); GLOAD4(ta1, tr + 64 + lane); \
        GLOAD4(ta2, tr + 128 + lane); GLOAD4(ta3, tr + cid3); } while (0)
    #define ISSUE_B(r) do { const float4* xr = xp + (size_t)(r) * rstep; \
                            const int4*   tr = tp + (size_t)(r) * rstep; \
        GLOAD4(xb0, xr + lane); GLOAD4(xb1, xr + 64 + lane); \
        GLOAD4(xb2, xr + 128 + lane); GLOAD4(xb3, xr + cid3); \
        GLOAD4(tb0, tr + lane); GLOAD4(tb1, tr + 64 + lane); \
        GLOAD4(tb2, tr + 128 + lane); GLOAD4(tb3, tr + cid3); } while (0)

    float acc = 0.0f;
    float sn, sp;

    #define REDUCE() do { \
        _Pragma("unroll") \
        for (int off = 32; off > 0; off >>= 1) { \
            sn += __shfl_down(sn, off, 64); \
            sp += __shfl_down(sp, off, 64); \
        } \
        if (lane == 0) acc += sn * sp; \
    } while (0)

    // prologue: rows 0 and 1 in flight (16 loads, 16 KB/wave)
    ISSUE_A(0);
    ISSUE_B(1);

    // row 0: newest 8 outstanding = row1's -> row0 landed
    WAITVM(8);
    sn = 0.f; sp = 0.f;
    acc4w(xa0, ta0, 1.0f, sn, sp); acc4w(xa1, ta1, 1.0f, sn, sp);
    acc4w(xa2, ta2, 1.0f, sn, sp); acc4w(xa3, ta3, w3,  sn, sp);
    ISSUE_A(2);                    // refill slot A while reducing
    REDUCE();

    // row 1
    WAITVM(8);
    sn = 0.f; sp = 0.f;
    acc4w(xb0, tb0, 1.0f, sn, sp); acc4w(xb1, tb1, 1.0f, sn, sp);
    acc4w(xb2, tb2, 1.0f, sn, sp); acc4w(xb3, tb3, w3,  sn, sp);
    ISSUE_B(3);
    REDUCE();

    // row 2
    WAITVM(8);
    sn = 0.f; sp = 0.f;
    acc4w(xa0, ta0, 1.0f, sn, sp); acc4w(xa1, ta1, 1.0f, sn, sp);
    acc4w(xa2, ta2, 1.0f, sn, sp); acc4w(xa3, ta3, w3,  sn, sp);
    REDUCE();

    // row 3 — drain
    WAITVM(0);
    sn = 0.f; sp = 0.f;
    acc4w(xb0, tb0, 1.0f, sn, sp); acc4w(xb1, tb1, 1.0f, sn, sp);
    acc4w(xb2, tb2, 1.0f, sn, sp); acc4w(xb3, tb3, w3,  sn, sp);
    REDUCE();

    #undef ISSUE_A
    #undef ISSUE_B
    #undef REDUCE

    // ---- fused finish ----
    __shared__ float sacc[4];
    __shared__ int   slast;
    if (lane == 0) sacc[wv] = acc;
    __syncthreads();

    if (tid == 0) {
        block_out[blockIdx.x] = (sacc[0] + sacc[1]) + (sacc[2] + sacc[3]);
        __threadfence();                              // agent release: partial visible
        unsigned old = atomicAdd(done_counter, 1u);   // device-scope by default
        slast = (old == NBLOCKS - 1) ? 1 : 0;
    }
    __syncthreads();

    if (slast) {
        __threadfence();   // agent acquire: invalidate L1/L2, see all partials
        const float4* r4 = (const float4*)block_out;  // 512 float4
        float4 a0 = r4[tid];
        float4 a1 = r4[tid + 256];
        float v = (a0.x + a0.y) + (a0.z + a0.w)
                + (a1.x + a1.y) + (a1.z + a1.w);
        #pragma unroll
        for (int off = 32; off > 0; off >>= 1)
            v += __shfl_down(v, off, 64);
        __shared__ float sv[4];
        if (lane == 0) sv[wv] = v;
        __syncthreads();
        if (tid == 0) {
            float total = (sv[0] + sv[1]) + (sv[2] + sv[3]);
            out[0] = log1pf(total);
        }
    }
}

extern "C" void kernel_launch(void* const* d_in, const int* in_sizes, int n_in,
                              void* d_out, int out_size, void* d_ws, size_t ws_size,
                              hipStream_t stream) {
    const float* x = (const float*)d_in[0];
    const int*   t = (const int*)d_in[1];
    float* out     = (float*)d_out;

    // ws layout: [0] unsigned done_counter (zeroed each launch);
    //            [256 B ...] float block_out[NBLOCKS]
    unsigned* ctr       = (unsigned*)d_ws;
    float*    block_out = (float*)((char*)d_ws + 256);

    hipMemsetAsync(ctr, 0, sizeof(unsigned), stream);
    lsep_row_kernel<<<NBLOCKS, 256, 0, stream>>>(x, t, block_out, ctr, out);
}

// Round 8
// 268.368 us; speedup vs baseline: 1.2888x; 1.2888x over previous
//
#include <hip/hip_runtime.h>
#include <math.h>

#define BATCH   32768
#define NCLS    1000
#define NC4     250              // 1000/4 float4 chunks per row
#define NBLOCKS 2048
#define NWAVES  (NBLOCKS * 4)    // 8192 waves
#define RPW     (BATCH / NWAVES) // 4 rows per wave

// Proven (R5/R6): 'nt' on streamed loads = -23 us; sc1 null on top.
// Proven (R7): per-block __threadfence() (agent fence -> buffer_wbl2/inv on
// non-coherent XCD L2s) halves stream BW (75 -> 146 us). This round: fusion
// WITHOUT fences — inter-block handoff via device-scope atomics only
// (coherent-point ops, m20), ordered by a plain s_waitcnt vmcnt(0).
#define GLOAD4(dst, ptr) \
    asm volatile("global_load_dwordx4 %0, %1, off sc1 nt" : "=v"(dst) : "v"(ptr) : "memory")

// Counted wait + sched_barrier(0): rule #18 — without the barrier, hipcc
// hoists register-only consumers above an inline-asm waitcnt.
#define WAITVM(N) do { \
    asm volatile("s_waitcnt vmcnt(" #N ")" ::: "memory"); \
    __builtin_amdgcn_sched_barrier(0); \
} while (0)

// One transcendental per element; w=0 kills the contribution of clamped
// tail lanes exactly (adds 0.0f, bit-exact vs branching them off).
__device__ __forceinline__ void acc4w(float4 xv, int4 tv, float w,
                                      float& sn, float& sp) {
    float e0 = w * __expf(tv.x == 0 ? xv.x : -xv.x);
    float e1 = w * __expf(tv.y == 0 ? xv.y : -xv.y);
    float e2 = w * __expf(tv.z == 0 ? xv.z : -xv.z);
    float e3 = w * __expf(tv.w == 0 ? xv.w : -xv.w);
    sn += (tv.x == 0) ? e0 : 0.0f;  sp += (tv.x == 0) ? 0.0f : e0;
    sn += (tv.y == 0) ? e1 : 0.0f;  sp += (tv.y == 0) ? 0.0f : e1;
    sn += (tv.z == 0) ? e2 : 0.0f;  sp += (tv.z == 0) ? 0.0f : e2;
    sn += (tv.w == 0) ? e3 : 0.0f;  sp += (tv.w == 0) ? 0.0f : e3;
}

// Asm-enforced depth-16 'nt' pipeline (streaming core byte-identical to
// round 6, which ran ~75 us). Fence-free fused finish: one float atomicAdd
// per block to the global total (device-scope, performs at the coherent
// point -> cross-XCD visible without any cache maintenance), vmcnt(0) to
// order it before the done-counter atomic, last thread reads the total via
// a returning atomic and writes log1p. No __threadfence anywhere.
__global__ __launch_bounds__(256, 4) void lsep_row_kernel(
    const float* __restrict__ x,
    const int*   __restrict__ t,
    unsigned* __restrict__ done_counter,  // ws+0, zeroed via hipMemsetAsync
    float* __restrict__ total_sum,        // ws+4, zeroed via hipMemsetAsync
    float* __restrict__ out) {

    const int tid   = threadIdx.x;
    const int lane  = tid & 63;
    const int wv    = tid >> 6;
    const int gwave = blockIdx.x * 4 + wv;           // 0..NWAVES-1

    // chunk 3 is partial (250 = 3*64 + 58): lanes 58-63 load chunk 249
    // (in-bounds dummy) and contribute 0 via w3.
    const int   cid3 = (lane < 58) ? (192 + lane) : 249;
    const float w3   = (lane < 58) ? 1.0f : 0.0f;

    const size_t rstep = (size_t)NWAVES * NC4;       // float4 stride per +NWAVES rows
    const float4* xp = (const float4*)x + (size_t)gwave * NC4;
    const int4*   tp = (const int4*)t + (size_t)gwave * NC4;

    float4 xa0, xa1, xa2, xa3, xb0, xb1, xb2, xb3;
    int4   ta0, ta1, ta2, ta3, tb0, tb1, tb2, tb3;

    // Issue one row's 8 loads: x-burst then t-burst (longer per-stream runs).
    #define ISSUE_A(r) do { const float4* xr = xp + (size_t)(r) * rstep; \
                            const int4*   tr = tp + (size_t)(r) * rstep; \
        GLOAD4(xa0, xr + lane); GLOAD4(xa1, xr + 64 + lane); \
        GLOAD4(xa2, xr + 128 + lane); GLOAD4(xa3, xr + cid3); \
        GLOAD4(ta0, tr + lane); GLOAD4(ta1, tr + 64 + lane); \
        GLOAD4(ta2, tr + 128 + lane); GLOAD4(ta3, tr + cid3); } while (0)
    #define ISSUE_B(r) do { const float4* xr = xp + (size_t)(r) * rstep; \
                            const int4*   tr = tp + (size_t)(r) * rstep; \
        GLOAD4(xb0, xr + lane); GLOAD4(xb1, xr + 64 + lane); \
        GLOAD4(xb2, xr + 128 + lane); GLOAD4(xb3, xr + cid3); \
        GLOAD4(tb0, tr + lane); GLOAD4(tb1, tr + 64 + lane); \
        GLOAD4(tb2, tr + 128 + lane); GLOAD4(tb3, tr + cid3); } while (0)

    float acc = 0.0f;
    float sn, sp;

    #define REDUCE() do { \
        _Pragma("unroll") \
        for (int off = 32; off > 0; off >>= 1) { \
            sn += __shfl_down(sn, off, 64); \
            sp += __shfl_down(sp, off, 64); \
        } \
        if (lane == 0) acc += sn * sp; \
    } while (0)

    // prologue: rows 0 and 1 in flight (16 loads, 16 KB/wave)
    ISSUE_A(0);
    ISSUE_B(1);

    // row 0: newest 8 outstanding = row1's -> row0 landed
    WAITVM(8);
    sn = 0.f; sp = 0.f;
    acc4w(xa0, ta0, 1.0f, sn, sp); acc4w(xa1, ta1, 1.0f, sn, sp);
    acc4w(xa2, ta2, 1.0f, sn, sp); acc4w(xa3, ta3, w3,  sn, sp);
    ISSUE_A(2);                    // refill slot A while reducing
    REDUCE();

    // row 1
    WAITVM(8);
    sn = 0.f; sp = 0.f;
    acc4w(xb0, tb0, 1.0f, sn, sp); acc4w(xb1, tb1, 1.0f, sn, sp);
    acc4w(xb2, tb2, 1.0f, sn, sp); acc4w(xb3, tb3, w3,  sn, sp);
    ISSUE_B(3);
    REDUCE();

    // row 2
    WAITVM(8);
    sn = 0.f; sp = 0.f;
    acc4w(xa0, ta0, 1.0f, sn, sp); acc4w(xa1, ta1, 1.0f, sn, sp);
    acc4w(xa2, ta2, 1.0f, sn, sp); acc4w(xa3, ta3, w3,  sn, sp);
    REDUCE();

    // row 3 — drain
    WAITVM(0);
    sn = 0.f; sp = 0.f;
    acc4w(xb0, tb0, 1.0f, sn, sp); acc4w(xb1, tb1, 1.0f, sn, sp);
    acc4w(xb2, tb2, 1.0f, sn, sp); acc4w(xb3, tb3, w3,  sn, sp);
    REDUCE();

    #undef ISSUE_A
    #undef ISSUE_B
    #undef REDUCE

    // ---- fence-free fused finish ----
    __shared__ float sacc[4];
    if (lane == 0) sacc[wv] = acc;
    __syncthreads();

    if (tid == 0) {
        const float part = (sacc[0] + sacc[1]) + (sacc[2] + sacc[3]);
        atomicAdd(total_sum, part);       // device-scope, coherent point
        WAITVM(0);                        // add performed before counter bump
        unsigned old = atomicAdd(done_counter, 1u);
        if (old == NBLOCKS - 1u) {        // last block: all adds complete
            float tot = atomicAdd(total_sum, 0.0f);   // coherent read
            out[0] = log1pf(tot);
        }
    }
}

extern "C" void kernel_launch(void* const* d_in, const int* in_sizes, int n_in,
                              void* d_out, int out_size, void* d_ws, size_t ws_size,
                              hipStream_t stream) {
    const float* x = (const float*)d_in[0];
    const int*   t = (const int*)d_in[1];
    float* out     = (float*)d_out;

    // ws layout: [0..3] unsigned done_counter, [4..7] float total_sum —
    // one 8-byte async memset zeroes both each launch (graph-capture-safe).
    unsigned* ctr   = (unsigned*)d_ws;
    float*    total = (float*)((char*)d_ws + 4);

    hipMemsetAsync(d_ws, 0, 8, stream);
    lsep_row_kernel<<<NBLOCKS, 256, 0, stream>>>(x, t, ctr, total, out);
}

// Round 9
// 242.780 us; speedup vs baseline: 1.4247x; 1.1054x over previous
//
#include <hip/hip_runtime.h>
#include <math.h>

#define BATCH   32768
#define NCLS    1000
#define NC4     250              // 1000/4 float4 chunks per row
#define NBLOCKS 2048
#define NWAVES  (NBLOCKS * 4)    // 8192 waves
#define RPW     (BATCH / NWAVES) // 4 rows per wave

// Proven: 'nt' = -23 us (R5; stops single-touch reads evicting dirty fill
// lines); sc1 null on top (R6); fusion loses either way (R7 fenced -77,
// R8 fence-free -24 -> two-kernel form restored). This round's single
// variable vs R6: pipeline depth 2 -> 3 rows (16 -> 24 loads in flight,
// +50% aggregate outstanding/CU) — the first MLP dose-response measured
// in the post-nt regime.
#define GLOAD4(dst, ptr) \
    asm volatile("global_load_dwordx4 %0, %1, off sc1 nt" : "=v"(dst) : "v"(ptr) : "memory")

// Counted wait + sched_barrier(0): rule #18 — without the barrier, hipcc
// hoists register-only consumers above an inline-asm waitcnt.
#define WAITVM(N) do { \
    asm volatile("s_waitcnt vmcnt(" #N ")" ::: "memory"); \
    __builtin_amdgcn_sched_barrier(0); \
} while (0)

// One transcendental per element; w=0 kills the contribution of clamped
// tail lanes exactly (adds 0.0f, bit-exact vs branching them off).
__device__ __forceinline__ void acc4w(float4 xv, int4 tv, float w,
                                      float& sn, float& sp) {
    float e0 = w * __expf(tv.x == 0 ? xv.x : -xv.x);
    float e1 = w * __expf(tv.y == 0 ? xv.y : -xv.y);
    float e2 = w * __expf(tv.z == 0 ? xv.z : -xv.z);
    float e3 = w * __expf(tv.w == 0 ? xv.w : -xv.w);
    sn += (tv.x == 0) ? e0 : 0.0f;  sp += (tv.x == 0) ? 0.0f : e0;
    sn += (tv.y == 0) ? e1 : 0.0f;  sp += (tv.y == 0) ? 0.0f : e1;
    sn += (tv.z == 0) ? e2 : 0.0f;  sp += (tv.z == 0) ? 0.0f : e2;
    sn += (tv.w == 0) ? e3 : 0.0f;  sp += (tv.w == 0) ? 0.0f : e3;
}

// Asm-enforced depth-24 'nt' pipeline: three row-slots (A/B/C) of 8 dwordx4
// each; rows r+1 and r+2 are always in flight while row r is consumed.
__global__ __launch_bounds__(256, 4) void lsep_row_kernel(
    const float* __restrict__ x,
    const int*   __restrict__ t,
    float* __restrict__ wave_out) {

    const int tid   = threadIdx.x;
    const int lane  = tid & 63;
    const int gwave = blockIdx.x * 4 + (tid >> 6);   // 0..NWAVES-1

    // chunk 3 is partial (250 = 3*64 + 58): lanes 58-63 load chunk 249
    // (in-bounds dummy) and contribute 0 via w3.
    const int   cid3 = (lane < 58) ? (192 + lane) : 249;
    const float w3   = (lane < 58) ? 1.0f : 0.0f;

    const size_t rstep = (size_t)NWAVES * NC4;       // float4 stride per +NWAVES rows
    const float4* xp = (const float4*)x + (size_t)gwave * NC4;
    const int4*   tp = (const int4*)t + (size_t)gwave * NC4;

    float4 xa0, xa1, xa2, xa3, xb0, xb1, xb2, xb3, xc0, xc1, xc2, xc3;
    int4   ta0, ta1, ta2, ta3, tb0, tb1, tb2, tb3, tc0, tc1, tc2, tc3;

    // Issue one row's 8 loads into a slot: x-burst then t-burst.
    #define ISSUE(S, r) do { const float4* xr = xp + (size_t)(r) * rstep; \
                             const int4*   tr = tp + (size_t)(r) * rstep; \
        GLOAD4(x##S##0, xr + lane); GLOAD4(x##S##1, xr + 64 + lane); \
        GLOAD4(x##S##2, xr + 128 + lane); GLOAD4(x##S##3, xr + cid3); \
        GLOAD4(t##S##0, tr + lane); GLOAD4(t##S##1, tr + 64 + lane); \
        GLOAD4(t##S##2, tr + 128 + lane); GLOAD4(t##S##3, tr + cid3); } while (0)

    #define CONSUME(S) do { \
        acc4w(x##S##0, t##S##0, 1.0f, sn, sp); \
        acc4w(x##S##1, t##S##1, 1.0f, sn, sp); \
        acc4w(x##S##2, t##S##2, 1.0f, sn, sp); \
        acc4w(x##S##3, t##S##3, w3,  sn, sp); } while (0)

    float acc = 0.0f;
    float sn, sp;

    #define REDUCE() do { \
        _Pragma("unroll") \
        for (int off = 32; off > 0; off >>= 1) { \
            sn += __shfl_down(sn, off, 64); \
            sp += __shfl_down(sp, off, 64); \
        } \
        if (lane == 0) acc += sn * sp; \
    } while (0)

    // prologue: rows 0,1,2 in flight (24 loads, 24 KB/wave)
    ISSUE(a, 0);
    ISSUE(b, 1);
    ISSUE(c, 2);

    // row 0: 16 newest outstanding = rows 1,2 -> row 0 landed
    WAITVM(16);
    sn = 0.f; sp = 0.f;
    CONSUME(a);
    ISSUE(a, 3);                   // refill slot A; back to 24 in flight
    REDUCE();

    // row 1: rows 2,3 outstanding
    WAITVM(16);
    sn = 0.f; sp = 0.f;
    CONSUME(b);
    REDUCE();

    // row 2: row 3 outstanding
    WAITVM(8);
    sn = 0.f; sp = 0.f;
    CONSUME(c);
    REDUCE();

    // row 3 — drain
    WAITVM(0);
    sn = 0.f; sp = 0.f;
    CONSUME(a);
    REDUCE();

    if (lane == 0) wave_out[gwave] = acc;

    #undef ISSUE
    #undef CONSUME
    #undef REDUCE
}

// Single block reduces NWAVES partials: 8 independent float4 loads per
// thread (fully unrolled), shuffle + LDS reduce, log1p.
__global__ __launch_bounds__(256) void lsep_reduce_kernel(
    const float* __restrict__ wave_out,
    float* __restrict__ out) {

    const int tid = threadIdx.x;
    const float4* r4 = (const float4*)wave_out;   // NWAVES/4 = 2048 float4

    float4 a[8];
    #pragma unroll
    for (int j = 0; j < 8; ++j)
        a[j] = r4[tid + 256 * j];

    float v = 0.0f;
    #pragma unroll
    for (int j = 0; j < 8; ++j)
        v += (a[j].x + a[j].y) + (a[j].z + a[j].w);

    #pragma unroll
    for (int off = 32; off > 0; off >>= 1)
        v += __shfl_down(v, off, 64);

    __shared__ float sv[4];
    const int wave = tid >> 6;
    const int lane = tid & 63;
    if (lane == 0) sv[wave] = v;
    __syncthreads();

    if (tid == 0) {
        float total = (sv[0] + sv[1]) + (sv[2] + sv[3]);
        out[0] = log1pf(total);
    }
}

extern "C" void kernel_launch(void* const* d_in, const int* in_sizes, int n_in,
                              void* d_out, int out_size, void* d_ws, size_t ws_size,
                              hipStream_t stream) {
    const float* x = (const float*)d_in[0];
    const int*   t = (const int*)d_in[1];
    float* out     = (float*)d_out;
    float* wave_ws = (float*)d_ws;   // NWAVES floats = 32 KB

    lsep_row_kernel<<<NBLOCKS, 256, 0, stream>>>(x, t, wave_ws);
    lsep_reduce_kernel<<<1, 256, 0, stream>>>(wave_ws, out);
}